// Round 8
// baseline (313.868 us; speedup 1.0000x reference)
//
#include <hip/hip_runtime.h>
#include <math.h>

// MultiHeadAttentionMemory: B=256, F=4096, M=4096 memories.
// seq_len==1 => attention==identity => o = (z@Wv+bv)@Wo+bo  (Wq/Wk dead).
// Split-bf16 (bf16x3: ah*bh + ah*bl + al*bh) MFMA for the 3 precision-
// sensitive GEMMs; plain bf16 MFMA for z_hat = w@mem.
// R8: BM=256 x BN=64 x BK=64, 512-thread 8-wave blocks, grid (64,1,8) =
// 512 blocks = 2 blocks/CU = 4 waves/SIMD (TLP covers barrier drains).
// All B operands reg-staged from RAW fp32 (transpose/split fused in-GEMM);
// no separate weight/memory split passes. reduce+softmax fused.
#define MB 256
#define FF 4096

typedef __attribute__((ext_vector_type(8))) short short8v;
typedef __attribute__((ext_vector_type(4))) short short4v;
typedef __attribute__((ext_vector_type(16))) float f32x16;

__device__ __forceinline__ unsigned short bf16_rne(float f) {
    unsigned u = __builtin_bit_cast(unsigned, f);
    u += 0x7fffu + ((u >> 16) & 1u);
    return (unsigned short)(u >> 16);
}
__device__ __forceinline__ float bf16_f(unsigned short h) {
    unsigned u = ((unsigned)h) << 16;
    return __builtin_bit_cast(float, u);
}

// ---------------- reductions ----------------
__device__ __forceinline__ float block_reduce_sum(float v, float* red) {
    const int tid = threadIdx.x;
    red[tid] = v; __syncthreads();
    for (int s = 128; s > 0; s >>= 1) {
        if (tid < s) red[tid] += red[tid + s];
        __syncthreads();
    }
    float r = red[0]; __syncthreads();
    return r;
}
__device__ __forceinline__ float block_reduce_max(float v, float* red) {
    const int tid = threadIdx.x;
    red[tid] = v; __syncthreads();
    for (int s = 128; s > 0; s >>= 1) {
        if (tid < s) red[tid] = fmaxf(red[tid], red[tid + s]);
        __syncthreads();
    }
    float r = red[0]; __syncthreads();
    return r;
}

// dst[row] = max(||src[row,:]||, 1e-8)
__global__ __launch_bounds__(256) void rownorm_kernel(
    const float* __restrict__ src, float* __restrict__ dst, int ncols)
{
    __shared__ float red[256];
    const int row = blockIdx.x, tid = threadIdx.x;
    const float4* p = (const float4*)(src + (size_t)row * ncols);
    float s = 0.f;
    for (int i = tid; i < ncols / 4; i += 256) {
        float4 v = p[i];
        s += v.x * v.x + v.y * v.y + v.z * v.z + v.w * v.w;
    }
    float tot = block_reduce_sum(s, red);
    if (tid == 0) dst[row] = fmaxf(sqrtf(tot), 1e-8f);
}

// ---------------- fp32 -> bf16 hi/lo split (straight) ----------------
__global__ __launch_bounds__(256) void split_plain(
    const float* __restrict__ src, unsigned short* __restrict__ hi,
    unsigned short* __restrict__ lo)
{
    const size_t i4 = (size_t)blockIdx.x * 256 + threadIdx.x;
    const float4 v = *(const float4*)(src + i4 * 4);
    unsigned short h0 = bf16_rne(v.x), h1 = bf16_rne(v.y), h2 = bf16_rne(v.z), h3 = bf16_rne(v.w);
    short4v hv = { (short)h0, (short)h1, (short)h2, (short)h3 };
    *(short4v*)(hi + i4 * 4) = hv;
    short4v lv = { (short)bf16_rne(v.x - bf16_f(h0)), (short)bf16_rne(v.y - bf16_f(h1)),
                   (short)bf16_rne(v.z - bf16_f(h2)), (short)bf16_rne(v.w - bf16_f(h3)) };
    *(short4v*)(lo + i4 * 4) = lv;
}

// ---------------- MFMA GEMM, split-K, fp32-B reg-staged ----------------
// C[256][4096](->part) = A[256][4096] @ B, BM=256, BN=64, BK=64,
// K-chunk 512 (8 tiles). Block = 512 threads = 8 waves (4m x 2n),
// wave tile 64x32. grid (64, 1, 8) = 512 blocks = 2 blocks/CU.
// BPATH 1: B raw fp32 [k][n] (weights; zhat's mem). 8 stride-FF scalar loads
//          per thread per tile, split to bf16 hi/lo in-VALU -> blocked LDS.
// BPATH 3: B raw fp32 [n][k] (logits' mem rows). 2 float4 loads per thread.
// Blocked LDS per plane (8KB): byte (k8*64+n)*16 holds B[n][k8*8..k8*8+8).
template <int BPATH, int SPLIT>
__global__ __launch_bounds__(512, 4) void gemm_sk(
    const unsigned short* __restrict__ Ah, const unsigned short* __restrict__ Al,
    const float* __restrict__ B, float* __restrict__ part)
{
    constexpr int PLANES = SPLIT ? 2 : 1;
    constexpr int BUFBYTES = PLANES * 8192;
    __shared__ unsigned short Bs[2 * PLANES * 4096];  // 2 buffers

    const int tid = threadIdx.x;
    const int lane = tid & 63, w = tid >> 6;
    const int wm = w >> 1, wn = w & 1;
    const int bn0 = blockIdx.x * 64;
    const int k0 = blockIdx.z * 512;
    const int l31 = lane & 31;
    const int tk8 = tid >> 6, tn = tid & 63;  // staging element (k8 0..7, n 0..63)

    // staging bases
    const float* bB = nullptr;
    if constexpr (BPATH == 1)
        bB = B + (size_t)(k0 + tk8 * 8) * FF + bn0 + tn;     // [k][n]
    else
        bB = B + (size_t)(bn0 + tn) * FF + k0 + tk8 * 8;     // [n][k]

    float rB0, rB1, rB2, rB3, rB4, rB5, rB6, rB7;
    float sB0, sB1, sB2, sB3, sB4, sB5, sB6, sB7;

#define LOADB(S, T_)                                                          \
    {                                                                         \
        if constexpr (BPATH == 1) {                                           \
            const float* p_ = bB + (size_t)(T_) * 64 * FF;                    \
            S##B0 = p_[0 * FF]; S##B1 = p_[1 * FF];                           \
            S##B2 = p_[2 * FF]; S##B3 = p_[3 * FF];                           \
            S##B4 = p_[4 * FF]; S##B5 = p_[5 * FF];                           \
            S##B6 = p_[6 * FF]; S##B7 = p_[7 * FF];                           \
        } else {                                                              \
            const float* p_ = bB + (T_) * 64;                                 \
            const float4 f0_ = *(const float4*)p_;                            \
            const float4 f1_ = *(const float4*)(p_ + 4);                      \
            S##B0 = f0_.x; S##B1 = f0_.y; S##B2 = f0_.z; S##B3 = f0_.w;       \
            S##B4 = f1_.x; S##B5 = f1_.y; S##B6 = f1_.z; S##B7 = f1_.w;       \
        }                                                                     \
    }

#define WRITEB(S, BUF_)                                                       \
    {                                                                         \
        unsigned short h0_ = bf16_rne(S##B0), h1_ = bf16_rne(S##B1),          \
                       h2_ = bf16_rne(S##B2), h3_ = bf16_rne(S##B3),          \
                       h4_ = bf16_rne(S##B4), h5_ = bf16_rne(S##B5),          \
                       h6_ = bf16_rne(S##B6), h7_ = bf16_rne(S##B7);          \
        short8v hv_ = { (short)h0_, (short)h1_, (short)h2_, (short)h3_,       \
                        (short)h4_, (short)h5_, (short)h6_, (short)h7_ };     \
        *(short8v*)((char*)Bs + (BUF_) * BUFBYTES + tid * 16) = hv_;          \
        if constexpr (SPLIT) {                                                \
            short8v lv_ = { (short)bf16_rne(S##B0 - bf16_f(h0_)),             \
                            (short)bf16_rne(S##B1 - bf16_f(h1_)),             \
                            (short)bf16_rne(S##B2 - bf16_f(h2_)),             \
                            (short)bf16_rne(S##B3 - bf16_f(h3_)),             \
                            (short)bf16_rne(S##B4 - bf16_f(h4_)),             \
                            (short)bf16_rne(S##B5 - bf16_f(h5_)),             \
                            (short)bf16_rne(S##B6 - bf16_f(h6_)),             \
                            (short)bf16_rne(S##B7 - bf16_f(h7_)) };           \
            *(short8v*)((char*)Bs + (BUF_) * BUFBYTES + 8192 + tid * 16) = lv_; \
        }                                                                     \
    }

    // B fragment read: byte = ((KH*2 + (lane>>5))*64 + wn*32 + l31)*16
    const char* const fragbase =
        (const char*)Bs + (((lane >> 5) * 64) + wn * 32 + l31) * 16;
#define BFRAG(BUF_, P_, KH_)                                                  \
    (*(const short8v*)(fragbase + (BUF_) * BUFBYTES + (P_) * 8192 + (KH_) * 2048))

    // A pointers (register-direct, L2-resident planes)
    const size_t arow = (size_t)(wm * 64 + l31) * FF + k0 + (lane >> 5) * 8;
    const unsigned short* a0h = Ah + arow;
    const unsigned short* a1h = a0h + (size_t)32 * FF;
    const unsigned short* a0l = SPLIT ? (Al + arow) : a0h;
    const unsigned short* a1l = a0l + (size_t)32 * FF;

    f32x16 acc0 = 0.0f, acc1 = 0.0f;

#define MFMA(A_, B_, C_) C_ = __builtin_amdgcn_mfma_f32_32x32x16_bf16(A_, B_, C_, 0, 0, 0)
#define MMKH(BUF_, T_, KH_)                                                   \
    {                                                                         \
        const int o_ = (T_) * 64 + (KH_) * 16;                                \
        short8v A0h_ = *(const short8v*)(a0h + o_);                           \
        short8v A1h_ = *(const short8v*)(a1h + o_);                           \
        short8v bh_ = BFRAG(BUF_, 0, KH_);                                    \
        MFMA(A0h_, bh_, acc0); MFMA(A1h_, bh_, acc1);                         \
        if constexpr (SPLIT) {                                                \
            short8v bl_ = BFRAG(BUF_, 1, KH_);                                \
            short8v A0l_ = *(const short8v*)(a0l + o_);                       \
            short8v A1l_ = *(const short8v*)(a1l + o_);                       \
            MFMA(A0h_, bl_, acc0); MFMA(A1h_, bl_, acc1);                     \
            MFMA(A0l_, bh_, acc0); MFMA(A1l_, bh_, acc1);                     \
        }                                                                     \
    }
#define TILE(BUF_, T_) { MMKH(BUF_, T_, 0) MMKH(BUF_, T_, 1) MMKH(BUF_, T_, 2) MMKH(BUF_, T_, 3) }

    // prologue: tile 0 -> buf0
    LOADB(r, 0)
    WRITEB(r, 0)
    __syncthreads();

#pragma unroll
    for (int tp = 0; tp < 4; ++tp) {
        const int t = tp * 2;
        // even tile t (buf0); stage t+1 -> buf1
        LOADB(s, t + 1)
        __builtin_amdgcn_s_setprio(1);
        TILE(0, t)
        __builtin_amdgcn_s_setprio(0);
        WRITEB(s, 1)
        __syncthreads();
        // odd tile t+1 (buf1); stage t+2 -> buf0
        if (tp < 3) { LOADB(r, t + 2) }
        __builtin_amdgcn_s_setprio(1);
        TILE(1, t + 1)
        __builtin_amdgcn_s_setprio(0);
        if (tp < 3) { WRITEB(r, 0) }
        __syncthreads();
    }
#undef LOADB
#undef WRITEB
#undef BFRAG
#undef MFMA
#undef MMKH
#undef TILE

    float* pp = part + (size_t)blockIdx.z * (MB * FF);
    const int rbase = wm * 64 + 4 * (lane >> 5);
    const int c0 = bn0 + wn * 32 + l31;
#pragma unroll
    for (int r = 0; r < 16; ++r) {
        const int row0 = rbase + (r & 3) + 8 * (r >> 2);
        float* rp0 = pp + (size_t)row0 * FF + c0;
        rp0[0] = acc0[r];
        float* rp1 = rp0 + (size_t)32 * FF;
        rp1[0] = acc1[r];
    }
}

// ---------------- split-K reduce + epilogue ----------------
// MODE 0: +bias -> hi/lo planes.  MODE 1: +bias -> hi/lo + f32.
// MODE 3: plain -> f32.
template <int MODE>
__global__ __launch_bounds__(256) void reduce_k(
    const float* __restrict__ part, const float* __restrict__ bias,
    unsigned short* __restrict__ hi, unsigned short* __restrict__ lo,
    float* __restrict__ fout)
{
    const size_t idx4 = (size_t)blockIdx.x * 256 + threadIdx.x;
    const size_t base = idx4 * 4;
    float s0 = 0.f, s1 = 0.f, s2 = 0.f, s3 = 0.f;
#pragma unroll
    for (int c = 0; c < 8; ++c) {
        const float4 p = *(const float4*)(part + (size_t)c * (MB * FF) + base);
        s0 += p.x; s1 += p.y; s2 += p.z; s3 += p.w;
    }
    const int col = (int)(base & 4095);
    if constexpr (MODE == 0 || MODE == 1) {
        s0 += bias[col]; s1 += bias[col + 1]; s2 += bias[col + 2]; s3 += bias[col + 3];
        unsigned short h0 = bf16_rne(s0), h1 = bf16_rne(s1), h2 = bf16_rne(s2), h3 = bf16_rne(s3);
        short4v hv = { (short)h0, (short)h1, (short)h2, (short)h3 };
        *(short4v*)(hi + base) = hv;
        short4v lv = { (short)bf16_rne(s0 - bf16_f(h0)), (short)bf16_rne(s1 - bf16_f(h1)),
                       (short)bf16_rne(s2 - bf16_f(h2)), (short)bf16_rne(s3 - bf16_f(h3)) };
        *(short4v*)(lo + base) = lv;
        if constexpr (MODE == 1) {
            float4 o = { s0, s1, s2, s3 };
            *(float4*)(fout + base) = o;
        }
    } else {
        float4 o = { s0, s1, s2, s3 };
        *(float4*)(fout + base) = o;
    }
}

// ---------------- fused: split-K reduce + cosine scale + softmax +
//                  shrinkage + renorm + entropy -> w_hi (bf16) ----------------
__global__ __launch_bounds__(256) void reduce_softmax(
    const float* __restrict__ part, const float* __restrict__ zn,
    const float* __restrict__ mn, unsigned short* __restrict__ w_hi,
    float* __restrict__ rowent)
{
    constexpr float THRESH = 1.0f / 4096.0f;
    constexpr float EPS = 1e-12f;
    __shared__ float srow[4096];
    __shared__ float red[256];
    const int row = blockIdx.x, tid = threadIdx.x;
    const float zr = zn[row];

    // reduce the 8 split-K partials and apply cosine scaling (same op order
    // as the previous reduce_k<2>: ascending-c sum, then divide).
    for (int i = tid; i < 1024; i += 256) {
        float s0 = 0.f, s1 = 0.f, s2 = 0.f, s3 = 0.f;
#pragma unroll
        for (int c = 0; c < 8; ++c) {
            const float4 p = *(const float4*)(part + (size_t)c * (MB * FF)
                                              + (size_t)row * FF + i * 4);
            s0 += p.x; s1 += p.y; s2 += p.z; s3 += p.w;
        }
        const float4 mv = *(const float4*)(mn + i * 4);
        float4 o = { s0 / (zr * mv.x), s1 / (zr * mv.y),
                     s2 / (zr * mv.z), s3 / (zr * mv.w) };
        *(float4*)(srow + i * 4) = o;
    }
    __syncthreads();

    float m = -INFINITY;
    for (int i = tid; i < FF; i += 256) m = fmaxf(m, srow[i]);
    m = block_reduce_max(m, red);

    float s = 0.f;
    for (int i = tid; i < FF; i += 256) {
        float e = expf(srow[i] - m);
        srow[i] = e; s += e;
    }
    s = block_reduce_sum(s, red);
    const float inv = 1.0f / s;

    float s2 = 0.f;
    for (int i = tid; i < FF; i += 256) {
        float ww = srow[i] * inv;
        float d = ww - THRESH;
        float w2 = fmaxf(d, 0.f) * ww / (fabsf(d) + EPS);
        srow[i] = w2; s2 += w2;
    }
    __syncthreads();
    s2 = block_reduce_sum(s2, red);
    const float inv2 = 1.0f / fmaxf(s2, EPS);

    float ent = 0.f;
    for (int i = tid; i < FF; i += 256) {
        float w3 = srow[i] * inv2;
        w_hi[(size_t)row * FF + i] = bf16_rne(w3);
        ent -= w3 * logf(w3 + EPS);
    }
    ent = block_reduce_sum(ent, red);
    if (tid == 0) rowent[row] = ent;
}

__global__ __launch_bounds__(256) void loss_kernel(
    const float* __restrict__ rowent, float* __restrict__ out)
{
    __shared__ float red[256];
    const int tid = threadIdx.x;
    float tot = block_reduce_sum(rowent[tid], red);
    if (tid == 0) out[0] = (tot / 256.0f) * 0.0002f;
}

extern "C" void kernel_launch(void* const* d_in, const int* in_sizes, int n_in,
                              void* d_out, int out_size, void* d_ws, size_t ws_size,
                              hipStream_t stream)
{
    // inputs: x, memory, Wq, bq, Wk, bk, Wv, bv, Wo, bo
    const float* x   = (const float*)d_in[0];
    const float* mem = (const float*)d_in[1];
    const float* Wv  = (const float*)d_in[6];
    const float* bv  = (const float*)d_in[7];
    const float* Wo  = (const float*)d_in[8];
    const float* bo  = (const float*)d_in[9];
    float* out = (float*)d_out;

    char* ws = (char*)d_ws;
    float*          part  = (float*)(ws + 134217728ull);           // 32 MB (8 split-K partials)
    unsigned short* x_hi  = (unsigned short*)(ws + 167772160ull);  // 2 MB
    unsigned short* x_lo  = (unsigned short*)(ws + 169869312ull);
    unsigned short* v_hi  = (unsigned short*)(ws + 171966464ull);
    unsigned short* v_lo  = (unsigned short*)(ws + 174063616ull);
    unsigned short* o_hi  = (unsigned short*)(ws + 176160768ull);
    unsigned short* o_lo  = (unsigned short*)(ws + 178257920ull);
    float*          o_f32 = (float*)(ws + 180355072ull);           // 4 MB
    unsigned short* w_hi  = (unsigned short*)(ws + 188743680ull);  // 2 MB
    float*          zn    = (float*)(ws + 190840832ull);
    float*          mn    = zn + MB;
    float*          rowe  = mn + FF;

    const dim3 blk(256);
    const dim3 blkG(512);
    const dim3 gG(64, 1, 8);               // gemm: N/64, M/256, split-K 8
    const int gR = (MB * FF) / (4 * 256);  // 1024

    // prep: x split; mem row norms (read-only)
    split_plain<<<gR, blk, 0, stream>>>(x, x_hi, x_lo);
    rownorm_kernel<<<FF, blk, 0, stream>>>(mem, mn, FF);

    // v = z @ Wv + bv   (B = raw fp32 Wv [k][n], split fused in-GEMM)
    gemm_sk<1, 1><<<gG, blkG, 0, stream>>>(x_hi, x_lo, Wv, part);
    reduce_k<0><<<gR, blk, 0, stream>>>(part, bv, v_hi, v_lo, nullptr);

    // o = v @ Wo + bo
    gemm_sk<1, 1><<<gG, blkG, 0, stream>>>(v_hi, v_lo, Wo, part);
    reduce_k<1><<<gR, blk, 0, stream>>>(part, bo, o_hi, o_lo, o_f32);

    // logits = (o @ mem^T) / (zn x mn)  (B = raw fp32 mem [n][k], BPATH3)
    rownorm_kernel<<<MB, blk, 0, stream>>>(o_f32, zn, FF);
    gemm_sk<3, 1><<<gG, blkG, 0, stream>>>(o_hi, o_lo, mem, part);
    // fused reduce + cosine scale + softmax/shrink/renorm/entropy
    reduce_softmax<<<MB, blk, 0, stream>>>(part, zn, mn, w_hi, rowe);

    // z_hat = w @ mem  (B = raw fp32 mem [k][n], round-only, plain bf16)
    gemm_sk<1, 0><<<gG, blkG, 0, stream>>>(w_hi, nullptr, mem, part);
    reduce_k<3><<<gR, blk, 0, stream>>>(part, nullptr, nullptr, nullptr, out);

    loss_kernel<<<1, blk, 0, stream>>>(rowe, out + (size_t)MB * FF);
}